// Round 2
// baseline (120.734 us; speedup 1.0000x reference)
//
#include <hip/hip_runtime.h>

#define N_NODES 200000
#define C 256
#define VC 16
#define VD 3
#define VDIM (VC * VD)   // 48
#define M_MOTIFS 50000
#define CAP 64           // per-motif slot capacity; Poisson(4) => P(count>64) ~ 1e-36

#define TM 16            // motifs per fused block (50000 = 3125 * 16, exact)
#define NODE_BLOCKS ((N_NODES + 255) / 256)       // 782
#define CVT_BLOCKS  ((C * C) / (256 * 4))         // 64 (float4 per thread)
#define FUSED_BLOCKS (M_MOTIFS / TM)              // 3125

typedef __attribute__((ext_vector_type(8))) __bf16 bf16x8;
typedef __attribute__((ext_vector_type(4))) float f32x4;

__device__ __forceinline__ unsigned short f2bf(float x) {
  unsigned u = __builtin_bit_cast(unsigned, x);
  u += 0x7fffu + ((u >> 16) & 1u);   // RNE
  return (unsigned short)(u >> 16);
}

// ---------------------------------------------------------------------------
// K1: slot-fill. rank = atomicAdd(cnt[m]); nodelist[m*64+rank] = i.
//     Extra blocks convert Ws->bf16.
// ---------------------------------------------------------------------------
__global__ __launch_bounds__(256) void fill_kernel(
    const int* __restrict__ seg, int* __restrict__ cnt,
    int* __restrict__ nodelist, const float* __restrict__ Ws,
    unsigned short* __restrict__ Wsb) {
  int b = blockIdx.x, t = threadIdx.x;
  if (b < NODE_BLOCKS) {
    int i = b * 256 + t;
    if (i < N_NODES) {
      int m = seg[i];
      int r = atomicAdd(&cnt[m], 1);
      if (r < CAP) nodelist[(size_t)m * CAP + r] = i;
    }
  } else {
    int i = ((b - NODE_BLOCKS) * 256 + t) * 4;
    float4 w = *(const float4*)(Ws + i);
    ushort4 o;
    o.x = f2bf(w.x); o.y = f2bf(w.y); o.z = f2bf(w.z); o.w = f2bf(w.w);
    *(ushort4*)(Wsb + i) = o;
  }
}

// ---------------------------------------------------------------------------
// K2: fused gather-mean + v-linear + bf16 MFMA GEMM.
//     Block = 16 motifs x all 256 output cols, 4 waves, 8KB LDS.
//     Phase 1: wave w gathers motifs [w*4, w*4+4): counts (1 load) + first 16
//       node ids of all 4 motifs (1 coalesced load, lane = motif*16+slot).
//       s-rows float4/lane, 4-way unrolled; mean -> bf16 -> XOR-swizzled LDS
//       row. v 16x16 linear fused via shuffles -> v_out directly.
//     Phase 2: 1 syncthreads; wave w computes cols [w*64, w*64+64) over the
//       16 rows: A-frag from swizzled LDS (conflict-free ds_read_b128), B
//       frags straight from L2-resident Wsb (128 KB, shared by all blocks).
// ---------------------------------------------------------------------------
__global__ __launch_bounds__(256, 6) void fused_kernel(
    const float* __restrict__ s, const float* __restrict__ v,
    const int* __restrict__ cnt, const int* __restrict__ nodelist,
    const unsigned short* __restrict__ Wsb, const float* __restrict__ bs,
    const float* __restrict__ Wv, const float* __restrict__ bv,
    float* __restrict__ s_out, float* __restrict__ v_out) {
  __shared__ unsigned short As[TM * C];   // 8 KB, rows XOR-swizzled by (row&7)<<3

  int tid = threadIdx.x;
  int wave = tid >> 6, lane = tid & 63;
  int bm0 = blockIdx.x * TM;
  int m0w = bm0 + wave * 4;

  // ---- phase 1: gather ----
  int kvv = 0;
  if (lane < 4) kvv = cnt[m0w + lane];
  // first 16 node ids of each of the 4 motifs, one coalesced load
  // (reading unused slots is safe: nodelist memory is always allocated;
  //  garbage ids are never shfl-consumed because loops bound by k)
  int mr = lane >> 4, sl = lane & 15;
  int idv = nodelist[(size_t)(m0w + mr) * CAP + sl];

  for (int r = 0; r < 4; ++r) {
    int m = m0w + r;
    int k = __shfl(kvv, r, 64);
    int kc = min(k, CAP);
    int n16 = min(kc, 16);
    int rb = r * 16;
    float4 acc = make_float4(0.f, 0.f, 0.f, 0.f);
    float vacc = 0.f;
    int jj = 0;
    for (; jj + 4 <= n16; jj += 4) {
      int i0 = __shfl(idv, rb + jj + 0, 64);
      int i1 = __shfl(idv, rb + jj + 1, 64);
      int i2 = __shfl(idv, rb + jj + 2, 64);
      int i3 = __shfl(idv, rb + jj + 3, 64);
      float4 a = ((const float4*)(s + (size_t)i0 * C))[lane];
      float4 b = ((const float4*)(s + (size_t)i1 * C))[lane];
      float4 c = ((const float4*)(s + (size_t)i2 * C))[lane];
      float4 d = ((const float4*)(s + (size_t)i3 * C))[lane];
      acc.x += (a.x + b.x) + (c.x + d.x);
      acc.y += (a.y + b.y) + (c.y + d.y);
      acc.z += (a.z + b.z) + (c.z + d.z);
      acc.w += (a.w + b.w) + (c.w + d.w);
      if (lane < VDIM) {
        float va = v[(size_t)i0 * VDIM + lane];
        float vb = v[(size_t)i1 * VDIM + lane];
        float vc = v[(size_t)i2 * VDIM + lane];
        float vd = v[(size_t)i3 * VDIM + lane];
        vacc += (va + vb) + (vc + vd);
      }
    }
    for (; jj < n16; ++jj) {
      int i0 = __shfl(idv, rb + jj, 64);
      float4 a = ((const float4*)(s + (size_t)i0 * C))[lane];
      acc.x += a.x; acc.y += a.y; acc.z += a.z; acc.w += a.w;
      if (lane < VDIM) vacc += v[(size_t)i0 * VDIM + lane];
    }
    // ultra-rare: k > 16 (P ~ 3e-7 per motif); wave-uniform broadcast loads
    for (int j = 16; j < kc; ++j) {
      int i0 = nodelist[(size_t)m * CAP + j];
      float4 a = ((const float4*)(s + (size_t)i0 * C))[lane];
      acc.x += a.x; acc.y += a.y; acc.z += a.z; acc.w += a.w;
      if (lane < VDIM) vacc += v[(size_t)i0 * VDIM + lane];
    }

    float rc = 1.0f / (float)max(k, 1);
    ushort4 o;
    o.x = f2bf(acc.x * rc); o.y = f2bf(acc.y * rc);
    o.z = f2bf(acc.z * rc); o.w = f2bf(acc.w * rc);
    int rblk = (wave << 2) + r;
    *(ushort4*)&As[rblk * C + ((lane * 4) ^ ((rblk & 7) << 3))] = o;

    float vm = vacc * rc;   // lane c*3+d holds vmean[c][d]
    if (lane < VDIM) {
      int oo = lane / 3, d = lane - oo * 3;
      float vo = bv[oo];
#pragma unroll
      for (int c2 = 0; c2 < VC; ++c2)
        vo += Wv[oo * VC + c2] * __shfl(vm, c2 * 3 + d, 64);
      v_out[(size_t)m * VDIM + lane] = vo;
    }
  }

  __syncthreads();

  // ---- phase 2: GEMM. wave covers the 16 rows x its 64-col strip ----
  int rl = lane & 15, kq = (lane >> 4) * 8;
  int wn0 = wave * 64;
  int xorv = (rl & 7) << 3;          // read-side swizzle (row == rl)
  f32x4 acc4[4] = {};
#pragma unroll
  for (int k0 = 0; k0 < C; k0 += 32) {
    bf16x8 af = *(const bf16x8*)&As[rl * C + ((k0 + kq) ^ xorv)];
    bf16x8 bfr[4];
#pragma unroll
    for (int j = 0; j < 4; ++j)
      bfr[j] = *(const bf16x8*)(Wsb + (size_t)(wn0 + j * 16 + rl) * C + k0 + kq);
#pragma unroll
    for (int j = 0; j < 4; ++j)
      acc4[j] = __builtin_amdgcn_mfma_f32_16x16x32_bf16(af, bfr[j], acc4[j],
                                                        0, 0, 0);
  }

  int rq = (lane >> 4) * 4;
#pragma unroll
  for (int j = 0; j < 4; ++j) {
    int cn = wn0 + j * 16 + rl;
    float bias = bs[cn];
#pragma unroll
    for (int rr = 0; rr < 4; ++rr) {
      int gm = bm0 + rq + rr;    // M_MOTIFS % TM == 0: no guard needed
      s_out[(size_t)gm * C + cn] = acc4[j][rr] + bias;
    }
  }
}

extern "C" void kernel_launch(void* const* d_in, const int* in_sizes, int n_in,
                              void* d_out, int out_size, void* d_ws, size_t ws_size,
                              hipStream_t stream) {
  const float* s  = (const float*)d_in[0];
  const float* v  = (const float*)d_in[1];
  const int*   seg = (const int*)d_in[2];
  const float* Ws = (const float*)d_in[3];
  const float* bs = (const float*)d_in[4];
  const float* Wv = (const float*)d_in[5];
  const float* bv = (const float*)d_in[6];

  float* out   = (float*)d_out;
  float* s_out = out;
  float* v_out = out + (size_t)M_MOTIFS * C;

  // ws layout (~13.1 MB): [cnt M][nodelist M*CAP][Wsb C*C bf16]
  int* cnt      = (int*)d_ws;
  int* nodelist = cnt + M_MOTIFS;
  unsigned short* Wsb = (unsigned short*)(nodelist + (size_t)M_MOTIFS * CAP);

  hipMemsetAsync(cnt, 0, M_MOTIFS * sizeof(int), stream);
  fill_kernel<<<NODE_BLOCKS + CVT_BLOCKS, 256, 0, stream>>>(seg, cnt, nodelist,
                                                            Ws, Wsb);
  fused_kernel<<<FUSED_BLOCKS, 256, 0, stream>>>(s, v, cnt, nodelist, Wsb, bs,
                                                 Wv, bv, s_out, v_out);
}

// Round 3
// 104.101 us; speedup vs baseline: 1.1598x; 1.1598x over previous
//
#include <hip/hip_runtime.h>

#define N_NODES 200000
#define C 256
#define VC 16
#define VD 3
#define VDIM (VC * VD)   // 48
#define M_MOTIFS 50000
#define M_PAD 50048      // padded rows for the 128-row GEMM tile
#define CAP 64           // per-motif slot capacity; Poisson(4) => P(count>64) ~ 1e-36

#define NODE_BLOCKS ((N_NODES + 255) / 256)       // 782
#define CVT_BLOCKS  ((C * C) / (256 * 4))         // 64 (float4 per thread)
#define GATHER_BLOCKS (M_MOTIFS / 4)              // 12500 (4 waves/block, 1 motif/wave)

typedef __attribute__((ext_vector_type(8))) __bf16 bf16x8;
typedef __attribute__((ext_vector_type(4))) float f32x4;

__device__ __forceinline__ unsigned short f2bf(float x) {
  unsigned u = __builtin_bit_cast(unsigned, x);
  u += 0x7fffu + ((u >> 16) & 1u);   // RNE
  return (unsigned short)(u >> 16);
}

// async global->LDS, 16B per lane; LDS dest = wave-uniform base + lane*16
__device__ __forceinline__ void async_copy16(const void* g, void* l) {
  __builtin_amdgcn_global_load_lds(
      (const __attribute__((address_space(1))) unsigned int*)g,
      (__attribute__((address_space(3))) unsigned int*)l, 16, 0, 0);
}

// ---------------------------------------------------------------------------
// K1: slot-fill. rank = atomicAdd(cnt[m]); nodelist[m*64+rank] = i.
//     Extra blocks convert Ws->bf16.
// ---------------------------------------------------------------------------
__global__ __launch_bounds__(256) void fill_kernel(
    const int* __restrict__ seg, int* __restrict__ cnt,
    int* __restrict__ nodelist, const float* __restrict__ Ws,
    unsigned short* __restrict__ Wsb) {
  int b = blockIdx.x, t = threadIdx.x;
  if (b < NODE_BLOCKS) {
    int i = b * 256 + t;
    if (i < N_NODES) {
      int m = seg[i];
      int r = atomicAdd(&cnt[m], 1);
      if (r < CAP) nodelist[(size_t)m * CAP + r] = i;
    }
  } else {
    int i = ((b - NODE_BLOCKS) * 256 + t) * 4;
    float4 w = *(const float4*)(Ws + i);
    ushort4 o;
    o.x = f2bf(w.x); o.y = f2bf(w.y); o.z = f2bf(w.z); o.w = f2bf(w.w);
    *(ushort4*)(Wsb + i) = o;
  }
}

// ---------------------------------------------------------------------------
// K2: gather + mean + fused v 16x16 linear. ONE WAVE PER MOTIF (50K waves).
//     Metadata = 2 INDEPENDENT loads (cnt + 16 slot ids). Row loads issued in
//     clamped batches of 4 (dup index min(j,k-1) -> L1 hit), accumulation
//     predicated by uniform k>j AFTER all loads of the batch are in flight.
// ---------------------------------------------------------------------------
__global__ __launch_bounds__(256) void gather_kernel(
    const float* __restrict__ s, const float* __restrict__ v,
    const int* __restrict__ cnt, const int* __restrict__ nodelist,
    const float* __restrict__ Wv, const float* __restrict__ bv,
    unsigned short* __restrict__ s_motif, float* __restrict__ v_out) {
  int m = (blockIdx.x * 256 + threadIdx.x) >> 6;   // exact: 12500*4 = 50000
  int lane = threadIdx.x & 63;
  int k = cnt[m];                                  // wave-uniform

  if (k == 0) {                                    // ~1.8% of motifs
    ushort4 z; z.x = z.y = z.z = z.w = 0;
    ((ushort4*)(s_motif + (size_t)m * C))[lane] = z;
    if (lane < VDIM) v_out[(size_t)m * VDIM + lane] = bv[lane / 3];
    return;
  }

  // independent of cnt: 16 candidate slot ids, one 64B coalesced read
  int idv = nodelist[(size_t)m * CAP + (lane & 15)];
  int km1 = k - 1;
  int kc = min(k, CAP);

  // ---- batch 0: slots 0..3 (clamped; duplicates are same-address L1 hits)
  int i0 = __shfl(idv, 0, 64);
  int i1 = __shfl(idv, min(1, km1), 64);
  int i2 = __shfl(idv, min(2, km1), 64);
  int i3 = __shfl(idv, min(3, km1), 64);
  float4 a0 = ((const float4*)(s + (size_t)i0 * C))[lane];
  float4 a1 = ((const float4*)(s + (size_t)i1 * C))[lane];
  float4 a2 = ((const float4*)(s + (size_t)i2 * C))[lane];
  float4 a3 = ((const float4*)(s + (size_t)i3 * C))[lane];
  float vb0 = 0.f, vb1 = 0.f, vb2 = 0.f, vb3 = 0.f;
  if (lane < VDIM) {
    vb0 = v[(size_t)i0 * VDIM + lane];
    vb1 = v[(size_t)i1 * VDIM + lane];
    vb2 = v[(size_t)i2 * VDIM + lane];
    vb3 = v[(size_t)i3 * VDIM + lane];
  }
  float4 acc = a0;
  float vacc = vb0;
  if (k > 1) { acc.x += a1.x; acc.y += a1.y; acc.z += a1.z; acc.w += a1.w; vacc += vb1; }
  if (k > 2) { acc.x += a2.x; acc.y += a2.y; acc.z += a2.z; acc.w += a2.w; vacc += vb2; }
  if (k > 3) { acc.x += a3.x; acc.y += a3.y; acc.z += a3.z; acc.w += a3.w; vacc += vb3; }

  // ---- batch 1: slots 4..7 (37% of motifs)
  if (k > 4) {
    int i4 = __shfl(idv, min(4, km1), 64);
    int i5 = __shfl(idv, min(5, km1), 64);
    int i6 = __shfl(idv, min(6, km1), 64);
    int i7 = __shfl(idv, min(7, km1), 64);
    float4 b4 = ((const float4*)(s + (size_t)i4 * C))[lane];
    float4 b5 = ((const float4*)(s + (size_t)i5 * C))[lane];
    float4 b6 = ((const float4*)(s + (size_t)i6 * C))[lane];
    float4 b7 = ((const float4*)(s + (size_t)i7 * C))[lane];
    float w4 = 0.f, w5 = 0.f, w6 = 0.f, w7 = 0.f;
    if (lane < VDIM) {
      w4 = v[(size_t)i4 * VDIM + lane];
      w5 = v[(size_t)i5 * VDIM + lane];
      w6 = v[(size_t)i6 * VDIM + lane];
      w7 = v[(size_t)i7 * VDIM + lane];
    }
    acc.x += b4.x; acc.y += b4.y; acc.z += b4.z; acc.w += b4.w; vacc += w4;
    if (k > 5) { acc.x += b5.x; acc.y += b5.y; acc.z += b5.z; acc.w += b5.w; vacc += w5; }
    if (k > 6) { acc.x += b6.x; acc.y += b6.y; acc.z += b6.z; acc.w += b6.w; vacc += w6; }
    if (k > 7) { acc.x += b7.x; acc.y += b7.y; acc.z += b7.z; acc.w += b7.w; vacc += w7; }
  }

  // ---- rare tail: slots 8.. (2% of motifs)
  if (k > 8) {
    int idv2 = nodelist[(size_t)m * CAP + lane];
    for (int j = 8; j < kc; ++j) {
      int ij = __shfl(idv2, j, 64);
      float4 a = ((const float4*)(s + (size_t)ij * C))[lane];
      acc.x += a.x; acc.y += a.y; acc.z += a.z; acc.w += a.w;
      if (lane < VDIM) vacc += v[(size_t)ij * VDIM + lane];
    }
  }

  float rc = 1.0f / (float)k;
  ushort4 o;
  o.x = f2bf(acc.x * rc); o.y = f2bf(acc.y * rc);
  o.z = f2bf(acc.z * rc); o.w = f2bf(acc.w * rc);
  ((ushort4*)(s_motif + (size_t)m * C))[lane] = o;

  float vm = vacc * rc;   // lane c*3+d holds vmean[c][d]
  if (lane < VDIM) {
    int oo = lane / 3, d = lane - oo * 3;
    float vo = bv[oo];
#pragma unroll
    for (int c2 = 0; c2 < VC; ++c2)
      vo += Wv[oo * VC + c2] * __shfl(vm, c2 * 3 + d, 64);
    v_out[(size_t)m * VDIM + lane] = vo;
  }
}

// ---------------------------------------------------------------------------
// K3: bf16 MFMA GEMM with global_load_lds width=16 staging (round-0 verified).
//     128x128 tile, BK=32, 4 waves (2x2), each wave 4x4 of 16x16x32 MFMAs.
// ---------------------------------------------------------------------------
__global__ __launch_bounds__(256) void gemm_mfma_kernel(
    const unsigned short* __restrict__ A16,   // s_motif bf16 [M_PAD][256]
    const unsigned short* __restrict__ B16,   // Ws bf16 [256][256]
    const float* __restrict__ bs, float* __restrict__ out) {
  __shared__ unsigned short As[128 * 32];
  __shared__ unsigned short Bs[128 * 32];
  int tid = threadIdx.x;
  int wave = tid >> 6, lane = tid & 63;
  int m0 = blockIdx.x * 128;
  int n0 = blockIdx.y * 128;
  int wm = (wave >> 1) * 64, wn = (wave & 1) * 64;

  f32x4 acc[4][4] = {};

  int srow = lane >> 2;        // 0..15: row within a 16-row staging group
  int kc   = (lane & 3) * 8;   // k element offset (16B chunk)
  int rl = lane & 15;
  int kq = (lane >> 4) * 8;

  const unsigned short* Ag = A16 + (size_t)(m0 + wave * 32) * C;
  const unsigned short* Bg = B16 + (size_t)(n0 + wave * 32) * C;
  unsigned short* Al = As + wave * 32 * 32;
  unsigned short* Bl = Bs + wave * 32 * 32;

  for (int k0 = 0; k0 < C; k0 += 32) {
    async_copy16(Ag + (size_t)srow * C + k0 + kc, Al);
    async_copy16(Ag + (size_t)(16 + srow) * C + k0 + kc, Al + 16 * 32);
    async_copy16(Bg + (size_t)srow * C + k0 + kc, Bl);
    async_copy16(Bg + (size_t)(16 + srow) * C + k0 + kc, Bl + 16 * 32);
    __syncthreads();

    bf16x8 af[4], bfr[4];
#pragma unroll
    for (int i = 0; i < 4; ++i)
      af[i] = *(const bf16x8*)&As[(size_t)(wm + i * 16 + rl) * 32 + kq];
#pragma unroll
    for (int j = 0; j < 4; ++j)
      bfr[j] = *(const bf16x8*)&Bs[(size_t)(wn + j * 16 + rl) * 32 + kq];
#pragma unroll
    for (int i = 0; i < 4; ++i)
#pragma unroll
      for (int j = 0; j < 4; ++j)
        acc[i][j] = __builtin_amdgcn_mfma_f32_16x16x32_bf16(
            af[i], bfr[j], acc[i][j], 0, 0, 0);
    __syncthreads();
  }

  int rq = (lane >> 4) * 4;
#pragma unroll
  for (int j = 0; j < 4; ++j) {
    int cn = n0 + wn + j * 16 + rl;
    float bias = bs[cn];
#pragma unroll
    for (int i = 0; i < 4; ++i) {
#pragma unroll
      for (int r = 0; r < 4; ++r) {
        int gm = m0 + wm + i * 16 + rq + r;
        if (gm < M_MOTIFS) out[(size_t)gm * C + cn] = acc[i][j][r] + bias;
      }
    }
  }
}

extern "C" void kernel_launch(void* const* d_in, const int* in_sizes, int n_in,
                              void* d_out, int out_size, void* d_ws, size_t ws_size,
                              hipStream_t stream) {
  const float* s  = (const float*)d_in[0];
  const float* v  = (const float*)d_in[1];
  const int*   seg = (const int*)d_in[2];
  const float* Ws = (const float*)d_in[3];
  const float* bs = (const float*)d_in[4];
  const float* Wv = (const float*)d_in[5];
  const float* bv = (const float*)d_in[6];

  float* out   = (float*)d_out;
  float* s_out = out;
  float* v_out = out + (size_t)M_MOTIFS * C;

  // ws layout (~38.7 MB): [cnt M][nodelist M*CAP][Wsb C*C bf16][s_motif M_PAD*C bf16]
  int* cnt      = (int*)d_ws;
  int* nodelist = cnt + M_MOTIFS;
  unsigned short* Wsb     = (unsigned short*)(nodelist + (size_t)M_MOTIFS * CAP);
  unsigned short* s_motif = Wsb + (size_t)C * C;
  // byte offsets: Wsb = 13,000,000 (16B-aligned); s_motif = 13,131,072 (16B-aligned)

  hipMemsetAsync(cnt, 0, M_MOTIFS * sizeof(int), stream);
  fill_kernel<<<NODE_BLOCKS + CVT_BLOCKS, 256, 0, stream>>>(seg, cnt, nodelist,
                                                            Ws, Wsb);
  gather_kernel<<<GATHER_BLOCKS, 256, 0, stream>>>(s, v, cnt, nodelist, Wv, bv,
                                                   s_motif, v_out);
  {
    dim3 grid(M_PAD / 128, C / 128);   // 391 x 2
    gemm_mfma_kernel<<<grid, 256, 0, stream>>>(s_motif, Wsb, bs, s_out);
  }
}